// Round 7
// baseline (4751.878 us; speedup 1.0000x reference)
//
#include <hip/hip_runtime.h>
#include <cstdint>
#include <cstddef>

#define B_ 8
#define N_ 4096
#define K_ 20
#define SUBS 8
#define RPB 32            // 256 threads / SUBS
#define MT1 1024
#define MT2 128

// separately-rounded multiply-add (numpy einsum-noopt style: no FMA contraction)
__device__ __forceinline__ float madd(float a, float b, float acc) {
  return __fadd_rn(acc, __fmul_rn(a, b));
}

// np-style sum of 3 squares: mul + sequential adds, no fma contraction
__device__ __forceinline__ float xx3f(float a, float b, float c) {
  return __fadd_rn(__fadd_rn(__fmul_rn(a, a), __fmul_rn(b, b)), __fmul_rn(c, c));
}

// ---------- top-k (maximize score, stable: value desc then index asc) ----------
__device__ __forceinline__ void topk_insert_max(float (&kp)[K_], int (&ki)[K_], float p, int m) {
  kp[K_ - 1] = p; ki[K_ - 1] = m;
#pragma unroll
  for (int t = K_ - 1; t > 0; --t) {
    if (kp[t] > kp[t - 1]) {
      float tp = kp[t]; kp[t] = kp[t - 1]; kp[t - 1] = tp;
      int ti = ki[t]; ki[t] = ki[t - 1]; ki[t - 1] = ti;
    }
  }
}

__device__ __forceinline__ void topk_merge_store_max(const float* mD, const int* mI, int rl, int* op) {
  int h[SUBS];
#pragma unroll
  for (int s = 0; s < SUBS; ++s) h[s] = 0;
  for (int j = 0; j < K_; ++j) {
    float best = -3.39e38f; int bi = 0x7fffffff; int bs = 0;
#pragma unroll
    for (int s = 0; s < SUBS; ++s) {
      int hs = h[s];
      float dv = (hs < K_) ? mD[(rl * SUBS + s) * K_ + hs] : -3.4e38f;
      int   iv = (hs < K_) ? mI[(rl * SUBS + s) * K_ + hs] : 0x7fffffff;
      if (dv > best || (dv == best && iv < bi)) { best = dv; bi = iv; bs = s; }
    }
    op[j] = bi;
#pragma unroll
    for (int s = 0; s < SUBS; ++s) h[s] += (s == bs) ? 1 : 0;
  }
}

// ---------- stage 1 KNN (C=3, einsum-noopt mul+add chain, reference formula) ----------
__global__ __launch_bounds__(256) void knn1_kernel(const float* __restrict__ x, int* __restrict__ idxo) {
  __shared__ double2 smem2[2560];                 // 40 KiB union
  float4* tile = (float4*)smem2;
  float*  mD = (float*)smem2;
  int*    mI = (int*)(mD + RPB * SUBS * K_);
  int bid = blockIdx.x;
  int b = bid / (N_ / RPB);
  int r0 = (bid % (N_ / RPB)) * RPB;
  int tid = threadIdx.x;
  int rl = tid / SUBS, sub = tid % SUBS;
  int row = r0 + rl;
  const float* xb = x + (size_t)b * 3 * N_;
  float ox = xb[row], oy = xb[N_ + row], oz = xb[2 * N_ + row];
  float nxxn = -xx3f(ox, oy, oz);
  float kp[K_]; int ki[K_];
#pragma unroll
  for (int t = 0; t < K_; ++t) { kp[t] = -3.0e38f; ki[t] = 0x7fffffff; }
  for (int t0 = 0; t0 < N_; t0 += MT1) {
    __syncthreads();
    for (int l = tid; l < MT1; l += 256) {
      float4 p;
      p.x = xb[t0 + l]; p.y = xb[N_ + t0 + l]; p.z = xb[2 * N_ + t0 + l];
      p.w = xx3f(p.x, p.y, p.z);
      tile[l] = p;
    }
    __syncthreads();
#pragma unroll 2
    for (int mi = sub; mi < MT1; mi += SUBS) {
      float4 p = tile[mi];
      // einsum-noopt: each product rounded, adds rounded, c ascending
      float d = __fmul_rn(ox, p.x);
      d = madd(oy, p.y, d);
      d = madd(oz, p.z, d);
      float pr = __fsub_rn(__fadd_rn(nxxn, __fadd_rn(d, d)), p.w);
      if (pr > kp[K_ - 1]) topk_insert_max(kp, ki, pr, t0 + mi);
    }
  }
  __syncthreads();
  int li = rl * SUBS + sub;
#pragma unroll
  for (int t = 0; t < K_; ++t) { mD[li * K_ + t] = kp[t]; mI[li * K_ + t] = ki[t]; }
  __syncthreads();
  if (sub == 0) topk_merge_store_max(mD, mI, rl, idxo + ((size_t)b * N_ + row) * K_);
}

// ---------- stage 2 KNN (C=64, einsum-noopt mul+add chain) ----------
__global__ __launch_bounds__(256) void knn2_kernel(const float* __restrict__ x1f,
                                                   const float* __restrict__ xxf,
                                                   int* __restrict__ idxo) {
  __shared__ double2 smem2[2560];
  float* tile = (float*)smem2;                    // MT2*68 floats
  float* txx  = tile + MT2 * 68;
  float* mD = (float*)smem2;
  int*   mI = (int*)(mD + RPB * SUBS * K_);
  int bid = blockIdx.x;
  int b = bid / (N_ / RPB);
  int r0 = (bid % (N_ / RPB)) * RPB;
  int tid = threadIdx.x;
  int rl = tid / SUBS, sub = tid % SUBS;
  int row = r0 + rl;
  const float* xrow = x1f + ((size_t)b * N_ + row) * 64;
  float own[64];
#pragma unroll
  for (int c4 = 0; c4 < 16; ++c4) {
    float4 t = ((const float4*)xrow)[c4];
    own[c4 * 4 + 0] = t.x; own[c4 * 4 + 1] = t.y;
    own[c4 * 4 + 2] = t.z; own[c4 * 4 + 3] = t.w;
  }
  float nxxn = -xxf[(size_t)b * N_ + row];
  float kp[K_]; int ki[K_];
#pragma unroll
  for (int t = 0; t < K_; ++t) { kp[t] = -3.0e38f; ki[t] = 0x7fffffff; }
  for (int t0 = 0; t0 < N_; t0 += MT2) {
    __syncthreads();
    for (int l = tid; l < MT2 * 16; l += 256) {
      int ml = l >> 4, c4 = l & 15;
      float4 tv = ((const float4*)(x1f + ((size_t)b * N_ + t0 + ml) * 64))[c4];
      *(float4*)&tile[ml * 68 + c4 * 4] = tv;
    }
    for (int l = tid; l < MT2; l += 256) txx[l] = xxf[(size_t)b * N_ + t0 + l];
    __syncthreads();
#pragma unroll 2
    for (int mi = sub; mi < MT2; mi += SUBS) {
      const float* xm = &tile[mi * 68];
      float d = 0.f;
#pragma unroll
      for (int c4 = 0; c4 < 16; ++c4) {
        float4 xm4 = *(const float4*)&xm[c4 * 4];
        d = madd(own[c4 * 4 + 0], xm4.x, d);
        d = madd(own[c4 * 4 + 1], xm4.y, d);
        d = madd(own[c4 * 4 + 2], xm4.z, d);
        d = madd(own[c4 * 4 + 3], xm4.w, d);
      }
      float pr = __fsub_rn(__fadd_rn(nxxn, __fadd_rn(d, d)), txx[mi]);
      if (pr > kp[K_ - 1]) topk_insert_max(kp, ki, pr, t0 + mi);
    }
  }
  __syncthreads();
  int li = rl * SUBS + sub;
#pragma unroll
  for (int t = 0; t < K_; ++t) { mD[li * K_ + t] = kp[t]; mI[li * K_ + t] = ki[t]; }
  __syncthreads();
  if (sub == 0) topk_merge_store_max(mD, mI, rl, idxo + ((size_t)b * N_ + row) * K_);
}

// ---------- y chains (einsum-noopt: mul+add, c ascending, acc starts 0) ----------
__device__ __forceinline__ float chain6(float w0, float w1, float w2, float w3, float w4, float w5,
                                        const float* fp) {
  float acc = __fmul_rn(w0, fp[0]);
  acc = madd(w1, fp[1], acc);
  acc = madd(w2, fp[2], acc);
  acc = madd(w3, fp[3], acc);
  acc = madd(w4, fp[4], acc);
  acc = madd(w5, fp[5], acc);
  return acc;
}

__device__ __forceinline__ float chain128(const float (&w)[128], const float* fp) {
  float acc = __fmul_rn(w[0], fp[0]);
#pragma unroll
  for (int c = 1; c < 128; ++c) acc = madd(w[c], fp[c], acc);
  return acc;
}

// numpy pairwise leaf combine: ((r0+r1)+(r2+r3)) + ((r4+r5)+(r6+r7))
__device__ __forceinline__ float leaf_combine(const float (&r8)[8]) {
  return __fadd_rn(__fadd_rn(__fadd_rn(r8[0], r8[1]), __fadd_rn(r8[2], r8[3])),
                   __fadd_rn(__fadd_rn(r8[4], r8[5]), __fadd_rn(r8[6], r8[7])));
}

// ---------- stage-1 leaf sums (numpy pairwise 80-leaf, 8 accumulators) ----------
template <int VAR>
__global__ __launch_bounds__(256) void leaf1_kernel(const float* __restrict__ x,
                                                    const float* __restrict__ W1,
                                                    const int* __restrict__ idx,
                                                    const float* __restrict__ pm,
                                                    float* __restrict__ leafbuf) {
  __shared__ float feat[2560];   // [4 leaves][80 f][8 c-slots]
  __shared__ int sidx[320];
  int b = blockIdx.x >> 8;
  int bg = blockIdx.x & 255;
  int n0 = bg * 16;
  int tid = threadIdx.x;
  const float* xb = x + (size_t)b * 3 * N_;
  for (int q = tid; q < 320; q += 256) sidx[q] = idx[((size_t)b * N_ + n0) * K_ + q];
  __syncthreads();
  for (int q = tid; q < 2560; q += 256) {
    int f = q >> 3, c = q & 7;
    int n = n0 + f / 20;
    float v = 0.f;
    if (c < 3) {
      int m = sidx[f];
      v = __fsub_rn(xb[c * N_ + m], xb[c * N_ + n]);
    } else if (c < 6) {
      v = xb[(c - 3) * N_ + n];
    }
    feat[q] = v;
  }
  __syncthreads();
  int o = tid & 63, lg = tid >> 6;
  float w0 = W1[o * 6 + 0], w1 = W1[o * 6 + 1], w2 = W1[o * 6 + 2];
  float w3 = W1[o * 6 + 3], w4 = W1[o * 6 + 4], w5 = W1[o * 6 + 5];
  float mu = VAR ? pm[o] : 0.f;
  const float* fb = feat + lg * 640;
  float r8[8];
#pragma unroll
  for (int jj = 0; jj < 8; ++jj) {
    float y = chain6(w0, w1, w2, w3, w4, w5, fb + jj * 8);
    if (VAR) { float t = __fsub_rn(y, mu); y = __fmul_rn(t, t); }
    r8[jj] = y;
  }
  for (int i = 1; i < 10; ++i) {
#pragma unroll
    for (int jj = 0; jj < 8; ++jj) {
      float y = chain6(w0, w1, w2, w3, w4, w5, fb + (i * 8 + jj) * 8);
      if (VAR) { float t = __fsub_rn(y, mu); y = __fmul_rn(t, t); }
      r8[jj] = __fadd_rn(r8[jj], y);
    }
  }
  int l = bg * 4 + lg;
  leafbuf[((size_t)b * 1024 + l) * 64 + o] = leaf_combine(r8);
}

// ---------- stage-2 leaf sums ----------
template <int VAR>
__global__ __launch_bounds__(64) void leaf2_kernel(const float* __restrict__ x1f,
                                                   const float* __restrict__ W2,
                                                   const int* __restrict__ idx,
                                                   const float* __restrict__ pm,
                                                   float* __restrict__ leafbuf) {
  __shared__ float feat[80][128];   // 40 KiB
  __shared__ int sidx[80];
  int b = blockIdx.x >> 10;
  int l = blockIdx.x & 1023;
  int t = threadIdx.x;
  float w[128];
#pragma unroll
  for (int c4 = 0; c4 < 32; ++c4) {
    float4 wv = *(const float4*)&W2[(size_t)t * 128 + c4 * 4];
    w[c4 * 4 + 0] = wv.x; w[c4 * 4 + 1] = wv.y;
    w[c4 * 4 + 2] = wv.z; w[c4 * 4 + 3] = wv.w;
  }
  for (int q = t; q < 80; q += 64) sidx[q] = idx[((size_t)b * N_ + l * 4) * K_ + q];
  __syncthreads();
  for (int r = 0; r < 4; ++r) {
    int n = l * 4 + r;
    float xn = x1f[((size_t)b * N_ + n) * 64 + t];
    for (int j = 0; j < 20; ++j) {
      int m = sidx[r * 20 + j];
      float xm = x1f[((size_t)b * N_ + m) * 64 + t];
      feat[r * 20 + j][t] = __fsub_rn(xm, xn);
      feat[r * 20 + j][64 + t] = xn;
    }
  }
  __syncthreads();
  float mu = VAR ? pm[t] : 0.f;
  float r8[8];
#pragma unroll
  for (int jj = 0; jj < 8; ++jj) {
    float y = chain128(w, feat[jj]);
    if (VAR) { float tt = __fsub_rn(y, mu); y = __fmul_rn(tt, tt); }
    r8[jj] = y;
  }
  for (int i = 1; i < 10; ++i) {
#pragma unroll
    for (int jj = 0; jj < 8; ++jj) {
      float y = chain128(w, feat[i * 8 + jj]);
      if (VAR) { float tt = __fsub_rn(y, mu); y = __fmul_rn(tt, tt); }
      r8[jj] = __fadd_rn(r8[jj], y);
    }
  }
  leafbuf[((size_t)b * 1024 + l) * 64 + t] = leaf_combine(r8);
}

// ---------- numpy pairwise tree over 1024 leaves + b-fold + mean/rs ----------
template <int MODE>   // 0: write mean -> pm[0..63]; 1: write rs -> pm[64..127]
__global__ __launch_bounds__(512) void tree_kernel(const float* __restrict__ lb,
                                                   float* __restrict__ pm) {
  __shared__ float red[512];
  int t = threadIdx.x;
  int b = t >> 6, o = t & 63;
  const float* base = lb + (size_t)b * 1024 * 64 + o;
  float part[32];
#pragma unroll
  for (int p = 0; p < 32; ++p) {
    float a[32];
#pragma unroll
    for (int q = 0; q < 32; ++q) a[q] = base[(size_t)(p * 32 + q) * 64];
#pragma unroll
    for (int lev = 16; lev >= 1; lev >>= 1) {
#pragma unroll
      for (int q = 0; q < 16; ++q) {
        if (q < lev) a[q] = __fadd_rn(a[2 * q], a[2 * q + 1]);
      }
    }
    part[p] = a[0];
  }
#pragma unroll
  for (int lev = 16; lev >= 1; lev >>= 1) {
#pragma unroll
    for (int q = 0; q < 16; ++q) {
      if (q < lev) part[q] = __fadd_rn(part[2 * q], part[2 * q + 1]);
    }
  }
  red[t] = part[0];
  __syncthreads();
  if (t < 64) {
    float acc = red[t];
#pragma unroll
    for (int bb = 1; bb < 8; ++bb) acc = __fadd_rn(acc, red[bb * 64 + t]);
    float mv = __fdiv_rn(acc, 655360.0f);
    if (MODE == 0) pm[t] = mv;
    else pm[64 + t] = __fdiv_rn(1.0f, __fsqrt_rn(__fadd_rn(mv, 1e-5f)));
  }
}

// ---------- stage-1 final: x1 + xx ----------
__global__ __launch_bounds__(256) void final1_kernel(const float* __restrict__ x,
                                                     const float* __restrict__ W1,
                                                     const int* __restrict__ idx,
                                                     const float* __restrict__ pm,
                                                     const float* __restrict__ g,
                                                     const float* __restrict__ be,
                                                     float* __restrict__ x1f,
                                                     float* __restrict__ xxf) {
  __shared__ float feat[640];   // [4 rows][20 j][8 c]
  __shared__ int sidx[80];
  __shared__ float xrow[4][64];
  int b = blockIdx.x >> 10;
  int rg = blockIdx.x & 1023;
  int n0 = rg * 4;
  int tid = threadIdx.x;
  const float* xb = x + (size_t)b * 3 * N_;
  for (int q = tid; q < 80; q += 256) sidx[q] = idx[((size_t)b * N_ + n0) * K_ + q];
  __syncthreads();
  for (int q = tid; q < 640; q += 256) {
    int f = q >> 3, c = q & 7;
    int n = n0 + f / 20;
    float v = 0.f;
    if (c < 3) {
      int m = sidx[f];
      v = __fsub_rn(xb[c * N_ + m], xb[c * N_ + n]);
    } else if (c < 6) {
      v = xb[(c - 3) * N_ + n];
    }
    feat[q] = v;
  }
  __syncthreads();
  int o = tid & 63, lr = tid >> 6;
  float w0 = W1[o * 6 + 0], w1 = W1[o * 6 + 1], w2 = W1[o * 6 + 2];
  float w3 = W1[o * 6 + 3], w4 = W1[o * 6 + 4], w5 = W1[o * 6 + 5];
  float mu = pm[o], rs = pm[64 + o], gg = g[o], bb = be[o];
  float mx = 0.f;
  for (int j = 0; j < 20; ++j) {
    float y = chain6(w0, w1, w2, w3, w4, w5, feat + (lr * 20 + j) * 8);
    float tt = __fsub_rn(y, mu);
    float yn = __fmul_rn(tt, rs);
    float yg = __fmul_rn(yn, gg);
    float yb = __fadd_rn(yg, bb);
    float val = (yb >= 0.f) ? yb : __fmul_rn(0.2f, yb);
    mx = (j == 0) ? val : fmaxf(mx, val);
  }
  int n = n0 + lr;
  x1f[((size_t)b * N_ + n) * 64 + o] = mx;
  xrow[lr][o] = mx;
  __syncthreads();
  if (tid < 4) {
    float acc = __fmul_rn(xrow[tid][0], xrow[tid][0]);
#pragma unroll
    for (int oo = 1; oo < 64; ++oo) acc = __fadd_rn(acc, __fmul_rn(xrow[tid][oo], xrow[tid][oo]));
    xxf[(size_t)b * N_ + n0 + tid] = acc;
  }
}

// ---------- stage-2 final: output (B,64,N) ----------
__global__ __launch_bounds__(64) void final2_kernel(const float* __restrict__ x1f,
                                                    const float* __restrict__ W2,
                                                    const int* __restrict__ idx,
                                                    const float* __restrict__ pm,
                                                    const float* __restrict__ g,
                                                    const float* __restrict__ be,
                                                    float* __restrict__ out) {
  __shared__ float feat[20][128];
  __shared__ int sidx[20];
  int b = blockIdx.x >> 12;
  int n = blockIdx.x & 4095;
  int t = threadIdx.x;
  float w[128];
#pragma unroll
  for (int c4 = 0; c4 < 32; ++c4) {
    float4 wv = *(const float4*)&W2[(size_t)t * 128 + c4 * 4];
    w[c4 * 4 + 0] = wv.x; w[c4 * 4 + 1] = wv.y;
    w[c4 * 4 + 2] = wv.z; w[c4 * 4 + 3] = wv.w;
  }
  if (t < 20) sidx[t] = idx[((size_t)b * N_ + n) * K_ + t];
  __syncthreads();
  float xn = x1f[((size_t)b * N_ + n) * 64 + t];
  for (int j = 0; j < 20; ++j) {
    int m = sidx[j];
    float xm = x1f[((size_t)b * N_ + m) * 64 + t];
    feat[j][t] = __fsub_rn(xm, xn);
    feat[j][64 + t] = xn;
  }
  __syncthreads();
  float mu = pm[t], rs = pm[64 + t], gg = g[t], bb = be[t];
  float mx = 0.f;
  for (int j = 0; j < 20; ++j) {
    float y = chain128(w, feat[j]);
    float tt = __fsub_rn(y, mu);
    float yn = __fmul_rn(tt, rs);
    float yg = __fmul_rn(yn, gg);
    float yb = __fadd_rn(yg, bb);
    float val = (yb >= 0.f) ? yb : __fmul_rn(0.2f, yb);
    mx = (j == 0) ? val : fmaxf(mx, val);
  }
  out[(size_t)b * 64 * N_ + (size_t)t * N_ + n] = mx;
}

extern "C" void kernel_launch(void* const* d_in, const int* in_sizes, int n_in,
                              void* d_out, int out_size, void* d_ws, size_t ws_size,
                              hipStream_t stream) {
  const float* x  = (const float*)d_in[0];
  const float* W1 = (const float*)d_in[1];
  const float* g1 = (const float*)d_in[2];
  const float* b1 = (const float*)d_in[3];
  const float* W2 = (const float*)d_in[4];
  const float* g2 = (const float*)d_in[5];
  const float* b2 = (const float*)d_in[6];
  float* out = (float*)d_out;
  const size_t PN = (size_t)B_ * N_;

  int*   idx     = (int*)d_ws;                  // PN*K ints
  float* x1f     = (float*)(idx + PN * K_);     // PN*64
  float* xxf     = x1f + PN * 64;               // PN
  float* leafbuf = xxf + PN;                    // 8*1024*64
  float* pm1     = leafbuf + (size_t)B_ * 1024 * 64;  // 128
  float* pm2     = pm1 + 128;                   // 128

  size_t need = (PN * K_ + PN * 64 + PN + (size_t)B_ * 1024 * 64 + 256) * 4;
  if (ws_size < need) return;

  const int knn_grid = B_ * (N_ / RPB);   // 1024

  // ---- stage 1 ----
  knn1_kernel<<<knn_grid, 256, 0, stream>>>(x, idx);
  leaf1_kernel<0><<<B_ * 256, 256, 0, stream>>>(x, W1, idx, pm1, leafbuf);
  tree_kernel<0><<<1, 512, 0, stream>>>(leafbuf, pm1);
  leaf1_kernel<1><<<B_ * 256, 256, 0, stream>>>(x, W1, idx, pm1, leafbuf);
  tree_kernel<1><<<1, 512, 0, stream>>>(leafbuf, pm1);
  final1_kernel<<<B_ * 1024, 256, 0, stream>>>(x, W1, idx, pm1, g1, b1, x1f, xxf);

  // ---- stage 2 ----
  knn2_kernel<<<knn_grid, 256, 0, stream>>>(x1f, xxf, idx);
  leaf2_kernel<0><<<B_ * 1024, 64, 0, stream>>>(x1f, W2, idx, pm2, leafbuf);
  tree_kernel<0><<<1, 512, 0, stream>>>(leafbuf, pm2);
  leaf2_kernel<1><<<B_ * 1024, 64, 0, stream>>>(x1f, W2, idx, pm2, leafbuf);
  tree_kernel<1><<<1, 512, 0, stream>>>(leafbuf, pm2);
  final2_kernel<<<B_ * N_, 64, 0, stream>>>(x1f, W2, idx, pm2, g2, b2, out);
}